// Round 10
// baseline (276.628 us; speedup 1.0000x reference)
//
#include <hip/hip_runtime.h>
#include <hip/hip_cooperative_groups.h>
#include <math.h>

namespace cg = cooperative_groups;

// Sizes fixed by the problem: B=2, T=512, E=384, H=64, dk=6.
#define SEQ_T   512
#define E_DIM   384
#define H_NUM   64
#define DKQ     6
#define NROWS   1024
#define QKV_ELEMS (NROWS*E_DIM)
#define NCHUNK  4
#define INV_SQRT6 0.40824829046386296f

// ---------------------------------------------------------------------------
// Quantum layer, analytic form (verified via Bloch algebra + Heisenberg
// push of Z through the CNOT ring):
//   z_i = cos(a_i)cos(b_i)*cos(x_i) - sin(b_i)*sin(x_i)
//   o0 = z1 z2 z3 z4 z5 ; o1 = z0 z1 ; o_k = o_{k-1} * z_k  (k=2..5)
// ---------------------------------------------------------------------------
__device__ __forceinline__ void qmap6(const float* __restrict__ in,
                                      const float* __restrict__ AB,
                                      float* __restrict__ out)
{
    float z[6];
#pragma unroll
    for (int i = 0; i < 6; ++i) {
        float s, c;
        sincosf(in[i], &s, &c);
        z[i] = AB[i] * c - AB[6 + i] * s;
    }
    float z01 = z[0] * z[1];
    float z12 = z[1] * z[2];
    float z34 = z[3] * z[4];
    out[0] = z12 * z34 * z[5];
    out[1] = z01;
    out[2] = z01 * z[2];
    out[3] = out[2] * z[3];
    out[4] = out[3] * z[4];
    out[5] = out[4] * z[5];
}

// ===========================================================================
// MEGA KERNEL: cooperative, grid 256 x 256 threads (4 waves/block, 1/CU).
// S1 QKV gemm+bias+qmap(+qscale)  -> qb,kb,vb
// S2 attention partial sums       -> part
// S3 cross-chunk reduce           -> merged
// S4 out gemm + bias              -> out
// LDS: xs 17.4KB + ws 25.6KB + kv 12KB = 55KB static.
// ===========================================================================
__global__ __launch_bounds__(256)
void mega_kernel(const float* __restrict__ x,
                 const float* __restrict__ Wq, const float* __restrict__ bq,
                 const float* __restrict__ Wk, const float* __restrict__ bk,
                 const float* __restrict__ Wv, const float* __restrict__ bv,
                 const float* __restrict__ Wo, const float* __restrict__ bo,
                 const float* __restrict__ qparams,
                 float* __restrict__ qb, float* __restrict__ kb, float* __restrict__ vb,
                 float* __restrict__ part, float* __restrict__ merged,
                 float* __restrict__ out)
{
    __shared__ __align__(16) float xs[64][68];    // [kk][row], 64 rows + pad
    __shared__ __align__(16) float ws[64][100];   // [kk][col], 96 cols + pad
    __shared__ __align__(16) float kv[2][128][12];

    cg::grid_group grid = cg::this_grid();

    const int tid  = threadIdx.x;
    const int lane = tid & 63;
    const int wid  = tid >> 6;       // wave 0..3
    const int bid  = blockIdx.x;

    // ---------------- S1: QKV gemm + qmap ----------------
    // 192 active blocks: tile 64 rows x 96 cols; wave panels 2x2 (32r x 48c).
    if (bid < 192) {
        const int bx = bid & 15;
        const int by = bid >> 4;          // 0..11
        const int n0 = bx * 64;
        const int sel = by >> 2;          // 0=Q,1=K,2=V
        const int e0 = (by & 3) * 96;

        const float* W; const float* bias; float* ob;
        if (sel == 0)      { W = Wq; bias = bq; ob = qb; }
        else if (sel == 1) { W = Wk; bias = bk; ob = kb; }
        else               { W = Wv; bias = bv; ob = vb; }

        float AB[12];
#pragma unroll
        for (int i = 0; i < 6; ++i) {
            const float a = qparams[i * 2 + 0];
            const float b = qparams[i * 2 + 1];
            AB[i]     = cosf(a) * cosf(b);
            AB[6 + i] = sinf(b);
        }

        float acc[4][6];
#pragma unroll
        for (int i = 0; i < 4; ++i)
#pragma unroll
            for (int j = 0; j < 6; ++j) acc[i][j] = 0.f;

        const int wr = (wid >> 1) * 32;   // wave row panel
        const int wc = (wid & 1) * 48;    // wave col panel
        const int tx = lane & 7;
        const int ty = lane >> 3;

        for (int kc = 0; kc < E_DIM; kc += 64) {
            // Stage A: 64 rows x 64 kk (1024 float4 slots / 256 thr = 4 each)
#pragma unroll
            for (int w = 0; w < 4; ++w) {
                const int idx = tid + 256 * w;
                const int row = idx & 63;
                const int kf  = idx >> 6;       // 0..15
                const float4 g = *reinterpret_cast<const float4*>(
                    x + (size_t)(n0 + row) * E_DIM + kc + kf * 4);
                xs[kf * 4 + 0][row] = g.x;
                xs[kf * 4 + 1][row] = g.y;
                xs[kf * 4 + 2][row] = g.z;
                xs[kf * 4 + 3][row] = g.w;
            }
            // Stage B: 96 cols x 64 kk (1536 slots / 256 thr = 6 each)
#pragma unroll
            for (int w = 0; w < 6; ++w) {
                const int idx = tid + 256 * w;
                const int c  = idx % 96;
                const int kf = idx / 96;        // 0..15
                const float4 g = *reinterpret_cast<const float4*>(
                    W + (size_t)(e0 + c) * E_DIM + kc + kf * 4);
                ws[kf * 4 + 0][c] = g.x;
                ws[kf * 4 + 1][c] = g.y;
                ws[kf * 4 + 2][c] = g.z;
                ws[kf * 4 + 3][c] = g.w;
            }
            __syncthreads();
#pragma unroll 8
            for (int kk = 0; kk < 64; ++kk) {
                const float4 a = *reinterpret_cast<const float4*>(&xs[kk][wr + ty * 4]);
                const float2 b0 = *reinterpret_cast<const float2*>(&ws[kk][wc + tx * 6 + 0]);
                const float2 b1 = *reinterpret_cast<const float2*>(&ws[kk][wc + tx * 6 + 2]);
                const float2 b2 = *reinterpret_cast<const float2*>(&ws[kk][wc + tx * 6 + 4]);
                const float av[4] = {a.x, a.y, a.z, a.w};
                const float bv6[6] = {b0.x, b0.y, b1.x, b1.y, b2.x, b2.y};
#pragma unroll
                for (int i = 0; i < 4; ++i)
#pragma unroll
                    for (int j = 0; j < 6; ++j) acc[i][j] += av[i] * bv6[j];
            }
            __syncthreads();
        }

        // Epilogue: bias + qmap (+ 1/sqrt(6) baked into Q), scatter (B,H,T,6)
        const int h = (e0 + wc) / 6 + tx;          // each thread = one head slice
        const float2 bi0 = *reinterpret_cast<const float2*>(bias + e0 + wc + tx * 6 + 0);
        const float2 bi1 = *reinterpret_cast<const float2*>(bias + e0 + wc + tx * 6 + 2);
        const float2 bi2 = *reinterpret_cast<const float2*>(bias + e0 + wc + tx * 6 + 4);
        const float qs = (sel == 0) ? INV_SQRT6 : 1.0f;
#pragma unroll
        for (int i = 0; i < 4; ++i) {
            const int n = n0 + wr + ty * 4 + i;    // b*512 + t
            const int b = n >> 9;
            const int t = n & 511;
            float y[6] = {acc[i][0] + bi0.x, acc[i][1] + bi0.y,
                          acc[i][2] + bi1.x, acc[i][3] + bi1.y,
                          acc[i][4] + bi2.x, acc[i][5] + bi2.y};
            float o[6];
            qmap6(y, AB, o);
            float* rp = ob + (((size_t)(b * H_NUM + h) * SEQ_T) + t) * DKQ;
            float2 w0 = {o[0] * qs, o[1] * qs};
            float2 w1 = {o[2] * qs, o[3] * qs};
            float2 w2 = {o[4] * qs, o[5] * qs};
            *reinterpret_cast<float2*>(rp + 0) = w0;
            *reinterpret_cast<float2*>(rp + 2) = w1;
            *reinterpret_cast<float2*>(rp + 4) = w2;
        }
    }
    grid.sync();

    // ---------------- S2: attention partial sums ----------------
    // 512 (bh, chunk) pairs over 256 blocks x 2 groups (128 thr each).
    {
        const int group = tid >> 7;       // 0..1
        const int t = tid & 127;
        const int pair = bid * 2 + group; // 0..511
        const int bh = pair >> 2;
        const int c  = pair & 3;

        {
            const float* kr = kb + ((size_t)bh * SEQ_T + c * 128 + t) * DKQ;
            const float* vr = vb + ((size_t)bh * SEQ_T + c * 128 + t) * DKQ;
            const float2 k0 = *reinterpret_cast<const float2*>(kr + 0);
            const float2 k1 = *reinterpret_cast<const float2*>(kr + 2);
            const float2 k2 = *reinterpret_cast<const float2*>(kr + 4);
            const float2 v0 = *reinterpret_cast<const float2*>(vr + 0);
            const float2 v1 = *reinterpret_cast<const float2*>(vr + 2);
            const float2 v2 = *reinterpret_cast<const float2*>(vr + 4);
            float4* kvp = reinterpret_cast<float4*>(&kv[group][t][0]);
            kvp[0] = make_float4(k0.x, k0.y, k1.x, k1.y);
            kvp[1] = make_float4(k2.x, k2.y, v0.x, v0.y);
            kvp[2] = make_float4(v1.x, v1.y, v2.x, v2.y);
        }

        float qrow[4][6];   // q pre-scaled by 1/sqrt(6) in S1
#pragma unroll
        for (int r = 0; r < 4; ++r) {
            const float* qp2 = qb + ((size_t)bh * SEQ_T + r * 128 + t) * DKQ;
            const float2 q0 = *reinterpret_cast<const float2*>(qp2 + 0);
            const float2 q1 = *reinterpret_cast<const float2*>(qp2 + 2);
            const float2 q2 = *reinterpret_cast<const float2*>(qp2 + 4);
            qrow[r][0] = q0.x; qrow[r][1] = q0.y;
            qrow[r][2] = q1.x; qrow[r][3] = q1.y;
            qrow[r][4] = q2.x; qrow[r][5] = q2.y;
        }
        __syncthreads();

        float accv[4][6];
        float den[4] = {0.f, 0.f, 0.f, 0.f};
#pragma unroll
        for (int r = 0; r < 4; ++r)
#pragma unroll
            for (int d = 0; d < 6; ++d) accv[r][d] = 0.f;

        const float4* kv4 = reinterpret_cast<const float4*>(&kv[group][0][0]);
#pragma unroll 2
        for (int s = 0; s < 128; ++s) {
            const float4 r0 = kv4[3 * s + 0];
            const float4 r1 = kv4[3 * s + 1];
            const float4 r2 = kv4[3 * s + 2];
#pragma unroll
            for (int r = 0; r < 4; ++r) {
                const float sc = qrow[r][0] * r0.x + qrow[r][1] * r0.y + qrow[r][2] * r0.z
                               + qrow[r][3] * r0.w + qrow[r][4] * r1.x + qrow[r][5] * r1.y;
                const float e = __expf(sc);
                den[r] += e;
                accv[r][0] += e * r1.z; accv[r][1] += e * r1.w;
                accv[r][2] += e * r2.x; accv[r][3] += e * r2.y;
                accv[r][4] += e * r2.z; accv[r][5] += e * r2.w;
            }
        }

#pragma unroll
        for (int r = 0; r < 4; ++r) {
            const int q = r * 128 + t;
            float4* pp = reinterpret_cast<float4*>(
                part + ((size_t)((c * SEQ_T + q) * 128 + bh)) * 8);
            pp[0] = make_float4(accv[r][0], accv[r][1], accv[r][2], accv[r][3]);
            pp[1] = make_float4(accv[r][4], accv[r][5], den[r], 0.f);
        }
    }
    grid.sync();

    // ---------------- S3: reduce partials -> merged ----------------
    {
        const int idx = bid * 256 + tid;   // 0..65535
        const int bh = idx & 127;
        const int q  = idx >> 7;

        float acc6[6] = {0.f, 0.f, 0.f, 0.f, 0.f, 0.f};
        float den = 0.f;
#pragma unroll
        for (int c = 0; c < NCHUNK; ++c) {
            const float4* pp = reinterpret_cast<const float4*>(
                part + ((size_t)((c * SEQ_T + q) * 128 + bh)) * 8);
            const float4 a = pp[0];
            const float4 b = pp[1];
            acc6[0] += a.x; acc6[1] += a.y; acc6[2] += a.z; acc6[3] += a.w;
            acc6[4] += b.x; acc6[5] += b.y; den += b.z;
        }
        const float r = 1.0f / den;
        const int b = bh >> 6;
        const int h = bh & 63;
        float* mp = merged + ((size_t)(b * SEQ_T + q)) * E_DIM + h * DKQ;
        float2 w0 = {acc6[0] * r, acc6[1] * r};
        float2 w1 = {acc6[2] * r, acc6[3] * r};
        float2 w2 = {acc6[4] * r, acc6[5] * r};
        *reinterpret_cast<float2*>(mp + 0) = w0;
        *reinterpret_cast<float2*>(mp + 2) = w1;
        *reinterpret_cast<float2*>(mp + 4) = w2;
    }
    grid.sync();

    // ---------------- S4: out gemm ----------------
    // 64 active blocks: tile 64 rows x 96 cols.
    if (bid < 64) {
        const int bx = bid & 15;
        const int ey = bid >> 4;          // 0..3
        const int n0 = bx * 64;
        const int e0 = ey * 96;

        float acc[4][6];
#pragma unroll
        for (int i = 0; i < 4; ++i)
#pragma unroll
            for (int j = 0; j < 6; ++j) acc[i][j] = 0.f;

        const int wr = (wid >> 1) * 32;
        const int wc = (wid & 1) * 48;
        const int tx = lane & 7;
        const int ty = lane >> 3;

        for (int kc = 0; kc < E_DIM; kc += 64) {
#pragma unroll
            for (int w = 0; w < 4; ++w) {
                const int idx = tid + 256 * w;
                const int row = idx & 63;
                const int kf  = idx >> 6;
                const float4 g = *reinterpret_cast<const float4*>(
                    merged + (size_t)(n0 + row) * E_DIM + kc + kf * 4);
                xs[kf * 4 + 0][row] = g.x;
                xs[kf * 4 + 1][row] = g.y;
                xs[kf * 4 + 2][row] = g.z;
                xs[kf * 4 + 3][row] = g.w;
            }
#pragma unroll
            for (int w = 0; w < 6; ++w) {
                const int idx = tid + 256 * w;
                const int c  = idx % 96;
                const int kf = idx / 96;
                const float4 g = *reinterpret_cast<const float4*>(
                    Wo + (size_t)(e0 + c) * E_DIM + kc + kf * 4);
                ws[kf * 4 + 0][c] = g.x;
                ws[kf * 4 + 1][c] = g.y;
                ws[kf * 4 + 2][c] = g.z;
                ws[kf * 4 + 3][c] = g.w;
            }
            __syncthreads();
#pragma unroll 8
            for (int kk = 0; kk < 64; ++kk) {
                const float4 a = *reinterpret_cast<const float4*>(&xs[kk][wr + ty * 4]);
                const float2 b0 = *reinterpret_cast<const float2*>(&ws[kk][wc + tx * 6 + 0]);
                const float2 b1 = *reinterpret_cast<const float2*>(&ws[kk][wc + tx * 6 + 2]);
                const float2 b2 = *reinterpret_cast<const float2*>(&ws[kk][wc + tx * 6 + 4]);
                const float av[4] = {a.x, a.y, a.z, a.w};
                const float bv6[6] = {b0.x, b0.y, b1.x, b1.y, b2.x, b2.y};
#pragma unroll
                for (int i = 0; i < 4; ++i)
#pragma unroll
                    for (int j = 0; j < 6; ++j) acc[i][j] += av[i] * bv6[j];
            }
            __syncthreads();
        }

        const float2 bi0 = *reinterpret_cast<const float2*>(bo + e0 + wc + tx * 6 + 0);
        const float2 bi1 = *reinterpret_cast<const float2*>(bo + e0 + wc + tx * 6 + 2);
        const float2 bi2 = *reinterpret_cast<const float2*>(bo + e0 + wc + tx * 6 + 4);
#pragma unroll
        for (int i = 0; i < 4; ++i) {
            const int n = n0 + wr + ty * 4 + i;
            float* rp = out + (size_t)n * E_DIM + e0 + wc + tx * 6;
            float2 w0 = {acc[i][0] + bi0.x, acc[i][1] + bi0.y};
            float2 w1 = {acc[i][2] + bi1.x, acc[i][3] + bi1.y};
            float2 w2 = {acc[i][4] + bi2.x, acc[i][5] + bi2.y};
            *reinterpret_cast<float2*>(rp + 0) = w0;
            *reinterpret_cast<float2*>(rp + 2) = w1;
            *reinterpret_cast<float2*>(rp + 4) = w2;
        }
    }
}

// ===========================================================================
// Fallback path (proven round-7 pipeline) in case cooperative launch is
// rejected by this ROCm's graph capture. Same math.
// ===========================================================================
__global__ __launch_bounds__(256)
void qmap_inplace(float* __restrict__ qb, const float* __restrict__ qparams)
{
    const int pid = blockIdx.x * 256 + threadIdx.x;
    float AB[12];
#pragma unroll
    for (int i = 0; i < 6; ++i) {
        const float a = qparams[i * 2 + 0];
        const float b = qparams[i * 2 + 1];
        AB[i]     = cosf(a) * cosf(b);
        AB[6 + i] = sinf(b);
    }
    float4* p = reinterpret_cast<float4*>(qb + (size_t)pid * 12);
    float4 g0 = p[0], g1 = p[1], g2 = p[2];
    float in0[6] = {g0.x, g0.y, g0.z, g0.w, g1.x, g1.y};
    float in1[6] = {g1.z, g1.w, g2.x, g2.y, g2.z, g2.w};
    float o0[6], o1[6];
    qmap6(in0, AB, o0);
    qmap6(in1, AB, o1);
    p[0] = make_float4(o0[0], o0[1], o0[2], o0[3]);
    p[1] = make_float4(o0[4], o0[5], o1[0], o1[1]);
    p[2] = make_float4(o1[2], o1[3], o1[4], o1[5]);
}

__global__ __launch_bounds__(64)
void fb_qkv_gemm(const float* __restrict__ x,
                 const float* __restrict__ Wq, const float* __restrict__ bq,
                 const float* __restrict__ Wk, const float* __restrict__ bk,
                 const float* __restrict__ Wv, const float* __restrict__ bv,
                 float* __restrict__ qb, float* __restrict__ kb, float* __restrict__ vb)
{
    __shared__ __align__(16) float xs[64][36];
    __shared__ __align__(16) float ws[64][52];
    const int tid = threadIdx.x;
    const int tx = tid & 7;
    const int ty = tid >> 3;
    const int n0 = blockIdx.x * 32;
    const int by = blockIdx.y;
    const int sel = by >> 3;
    const int e0 = (by & 7) * 48;

    const float* W; const float* bias; float* ob;
    if (sel == 0)      { W = Wq; bias = bq; ob = qb; }
    else if (sel == 1) { W = Wk; bias = bk; ob = kb; }
    else               { W = Wv; bias = bv; ob = vb; }

    float acc[4][6];
#pragma unroll
    for (int i = 0; i < 4; ++i)
#pragma unroll
        for (int j = 0; j < 6; ++j) acc[i][j] = 0.f;

    for (int kc = 0; kc < E_DIM; kc += 64) {
#pragma unroll
        for (int w = 0; w < 8; ++w) {
            const int idx = tid + 64 * w;
            const int row = idx & 31;
            const int kf  = idx >> 5;
            const float4 g = *reinterpret_cast<const float4*>(
                x + (size_t)(n0 + row) * E_DIM + kc + kf * 4);
            xs[kf * 4 + 0][row] = g.x; xs[kf * 4 + 1][row] = g.y;
            xs[kf * 4 + 2][row] = g.z; xs[kf * 4 + 3][row] = g.w;
        }
#pragma unroll
        for (int w = 0; w < 12; ++w) {
            const int idx = tid + 64 * w;
            const int c  = idx % 48;
            const int kf = idx / 48;
            const float4 g = *reinterpret_cast<const float4*>(
                W + (size_t)(e0 + c) * E_DIM + kc + kf * 4);
            ws[kf * 4 + 0][c] = g.x; ws[kf * 4 + 1][c] = g.y;
            ws[kf * 4 + 2][c] = g.z; ws[kf * 4 + 3][c] = g.w;
        }
        __syncthreads();
#pragma unroll 8
        for (int kk = 0; kk < 64; ++kk) {
            const float4 a = *reinterpret_cast<const float4*>(&xs[kk][ty * 4]);
            const float2 b0 = *reinterpret_cast<const float2*>(&ws[kk][tx * 6 + 0]);
            const float2 b1 = *reinterpret_cast<const float2*>(&ws[kk][tx * 6 + 2]);
            const float2 b2 = *reinterpret_cast<const float2*>(&ws[kk][tx * 6 + 4]);
            const float av[4] = {a.x, a.y, a.z, a.w};
            const float bv6[6] = {b0.x, b0.y, b1.x, b1.y, b2.x, b2.y};
#pragma unroll
            for (int i = 0; i < 4; ++i)
#pragma unroll
                for (int j = 0; j < 6; ++j) acc[i][j] += av[i] * bv6[j];
        }
        __syncthreads();
    }

    const int h = (e0 / 6) + tx;
    const float2 bi0 = *reinterpret_cast<const float2*>(bias + e0 + tx * 6 + 0);
    const float2 bi1 = *reinterpret_cast<const float2*>(bias + e0 + tx * 6 + 2);
    const float2 bi2 = *reinterpret_cast<const float2*>(bias + e0 + tx * 6 + 4);
#pragma unroll
    for (int i = 0; i < 4; ++i) {
        const int n = n0 + ty * 4 + i;
        const int b = n >> 9;
        const int t = n & 511;
        float* rp = ob + (((size_t)(b * H_NUM + h) * SEQ_T) + t) * DKQ;
        float2 w0 = {acc[i][0] + bi0.x, acc[i][1] + bi0.y};
        float2 w1 = {acc[i][2] + bi1.x, acc[i][3] + bi1.y};
        float2 w2 = {acc[i][4] + bi2.x, acc[i][5] + bi2.y};
        *reinterpret_cast<float2*>(rp + 0) = w0;
        *reinterpret_cast<float2*>(rp + 2) = w1;
        *reinterpret_cast<float2*>(rp + 4) = w2;
    }
}

__global__ __launch_bounds__(128)
void fb_attn_partial(const float* __restrict__ qb,
                     const float* __restrict__ kb,
                     const float* __restrict__ vb,
                     float* __restrict__ part)
{
    __shared__ __align__(16) float kv[128][12];
    const int bh = blockIdx.x;
    const int c  = blockIdx.y;
    const int t  = threadIdx.x;
    {
        const float* kr = kb + ((size_t)bh * SEQ_T + c * 128 + t) * DKQ;
        const float* vr = vb + ((size_t)bh * SEQ_T + c * 128 + t) * DKQ;
        const float2 k0 = *reinterpret_cast<const float2*>(kr + 0);
        const float2 k1 = *reinterpret_cast<const float2*>(kr + 2);
        const float2 k2 = *reinterpret_cast<const float2*>(kr + 4);
        const float2 v0 = *reinterpret_cast<const float2*>(vr + 0);
        const float2 v1 = *reinterpret_cast<const float2*>(vr + 2);
        const float2 v2 = *reinterpret_cast<const float2*>(vr + 4);
        float4* kvp = reinterpret_cast<float4*>(&kv[t][0]);
        kvp[0] = make_float4(k0.x, k0.y, k1.x, k1.y);
        kvp[1] = make_float4(k2.x, k2.y, v0.x, v0.y);
        kvp[2] = make_float4(v1.x, v1.y, v2.x, v2.y);
    }
    const float inv = INV_SQRT6;
    float qrow[4][6];
#pragma unroll
    for (int r = 0; r < 4; ++r) {
        const float* qp = qb + ((size_t)bh * SEQ_T + r * 128 + t) * DKQ;
        const float2 q0 = *reinterpret_cast<const float2*>(qp + 0);
        const float2 q1 = *reinterpret_cast<const float2*>(qp + 2);
        const float2 q2 = *reinterpret_cast<const float2*>(qp + 4);
        qrow[r][0] = q0.x * inv; qrow[r][1] = q0.y * inv;
        qrow[r][2] = q1.x * inv; qrow[r][3] = q1.y * inv;
        qrow[r][4] = q2.x * inv; qrow[r][5] = q2.y * inv;
    }
    __syncthreads();
    float accv[4][6];
    float den[4] = {0.f, 0.f, 0.f, 0.f};
#pragma unroll
    for (int r = 0; r < 4; ++r)
#pragma unroll
        for (int d = 0; d < 6; ++d) accv[r][d] = 0.f;
    const float4* kv4 = reinterpret_cast<const float4*>(&kv[0][0]);
#pragma unroll 2
    for (int s = 0; s < 128; ++s) {
        const float4 r0 = kv4[3 * s + 0];
        const float4 r1 = kv4[3 * s + 1];
        const float4 r2 = kv4[3 * s + 2];
#pragma unroll
        for (int r = 0; r < 4; ++r) {
            const float sc = qrow[r][0] * r0.x + qrow[r][1] * r0.y + qrow[r][2] * r0.z
                           + qrow[r][3] * r0.w + qrow[r][4] * r1.x + qrow[r][5] * r1.y;
            const float e = __expf(sc);
            den[r] += e;
            accv[r][0] += e * r1.z; accv[r][1] += e * r1.w;
            accv[r][2] += e * r2.x; accv[r][3] += e * r2.y;
            accv[r][4] += e * r2.z; accv[r][5] += e * r2.w;
        }
    }
#pragma unroll
    for (int r = 0; r < 4; ++r) {
        const int q = r * 128 + t;
        float4* pp = reinterpret_cast<float4*>(
            part + ((size_t)((c * SEQ_T + q) * 128 + bh)) * 8);
        pp[0] = make_float4(accv[r][0], accv[r][1], accv[r][2], accv[r][3]);
        pp[1] = make_float4(accv[r][4], accv[r][5], den[r], 0.f);
    }
}

__global__ __launch_bounds__(256)
void fb_attn_reduce(const float* __restrict__ part, float* __restrict__ merged)
{
    const int idx = blockIdx.x * 256 + threadIdx.x;
    const int bh = idx & 127;
    const int q  = idx >> 7;
    float acc[6] = {0.f, 0.f, 0.f, 0.f, 0.f, 0.f};
    float den = 0.f;
#pragma unroll
    for (int c = 0; c < NCHUNK; ++c) {
        const float4* pp = reinterpret_cast<const float4*>(
            part + ((size_t)((c * SEQ_T + q) * 128 + bh)) * 8);
        const float4 a = pp[0];
        const float4 b = pp[1];
        acc[0] += a.x; acc[1] += a.y; acc[2] += a.z; acc[3] += a.w;
        acc[4] += b.x; acc[5] += b.y; den += b.z;
    }
    const float r = 1.0f / den;
    const int b = bh >> 6;
    const int h = bh & 63;
    float* mp = merged + ((size_t)(b * SEQ_T + q)) * E_DIM + h * DKQ;
    float2 w0 = {acc[0] * r, acc[1] * r};
    float2 w1 = {acc[2] * r, acc[3] * r};
    float2 w2 = {acc[4] * r, acc[5] * r};
    *reinterpret_cast<float2*>(mp + 0) = w0;
    *reinterpret_cast<float2*>(mp + 2) = w1;
    *reinterpret_cast<float2*>(mp + 4) = w2;
}

__global__ __launch_bounds__(64)
void fb_out_gemm(const float* __restrict__ merged,
                 const float* __restrict__ Wo, const float* __restrict__ bo,
                 float* __restrict__ out)
{
    __shared__ __align__(16) float xs[64][36];
    __shared__ __align__(16) float ws[64][52];
    const int tid = threadIdx.x;
    const int tx = tid & 7;
    const int ty = tid >> 3;
    const int n0 = blockIdx.x * 32;
    const int e0 = blockIdx.y * 48;

    float acc[4][6];
#pragma unroll
    for (int i = 0; i < 4; ++i)
#pragma unroll
        for (int j = 0; j < 6; ++j) acc[i][j] = 0.f;

    for (int kc = 0; kc < E_DIM; kc += 64) {
#pragma unroll
        for (int w = 0; w < 8; ++w) {
            const int idx = tid + 64 * w;
            const int row = idx & 31;
            const int kf  = idx >> 5;
            const float4 g = *reinterpret_cast<const float4*>(
                merged + (size_t)(n0 + row) * E_DIM + kc + kf * 4);
            xs[kf * 4 + 0][row] = g.x; xs[kf * 4 + 1][row] = g.y;
            xs[kf * 4 + 2][row] = g.z; xs[kf * 4 + 3][row] = g.w;
        }
#pragma unroll
        for (int w = 0; w < 12; ++w) {
            const int idx = tid + 64 * w;
            const int c  = idx % 48;
            const int kf = idx / 48;
            const float4 g = *reinterpret_cast<const float4*>(
                Wo + (size_t)(e0 + c) * E_DIM + kc + kf * 4);
            ws[kf * 4 + 0][c] = g.x; ws[kf * 4 + 1][c] = g.y;
            ws[kf * 4 + 2][c] = g.z; ws[kf * 4 + 3][c] = g.w;
        }
        __syncthreads();
#pragma unroll 8
        for (int kk = 0; kk < 64; ++kk) {
            const float4 a = *reinterpret_cast<const float4*>(&xs[kk][ty * 4]);
            const float2 b0 = *reinterpret_cast<const float2*>(&ws[kk][tx * 6 + 0]);
            const float2 b1 = *reinterpret_cast<const float2*>(&ws[kk][tx * 6 + 2]);
            const float2 b2 = *reinterpret_cast<const float2*>(&ws[kk][tx * 6 + 4]);
            const float av[4] = {a.x, a.y, a.z, a.w};
            const float bv6[6] = {b0.x, b0.y, b1.x, b1.y, b2.x, b2.y};
#pragma unroll
            for (int i = 0; i < 4; ++i)
#pragma unroll
                for (int j = 0; j < 6; ++j) acc[i][j] += av[i] * bv6[j];
        }
        __syncthreads();
    }

    const float2 bi0 = *reinterpret_cast<const float2*>(bo + e0 + tx * 6 + 0);
    const float2 bi1 = *reinterpret_cast<const float2*>(bo + e0 + tx * 6 + 2);
    const float2 bi2 = *reinterpret_cast<const float2*>(bo + e0 + tx * 6 + 4);
#pragma unroll
    for (int i = 0; i < 4; ++i) {
        const int n = n0 + ty * 4 + i;
        float* rp = out + (size_t)n * E_DIM + e0 + tx * 6;
        float2 w0 = {acc[i][0] + bi0.x, acc[i][1] + bi0.y};
        float2 w1 = {acc[i][2] + bi1.x, acc[i][3] + bi1.y};
        float2 w2 = {acc[i][4] + bi2.x, acc[i][5] + bi2.y};
        *reinterpret_cast<float2*>(rp + 0) = w0;
        *reinterpret_cast<float2*>(rp + 2) = w1;
        *reinterpret_cast<float2*>(rp + 4) = w2;
    }
}

// ---------------------------------------------------------------------------
extern "C" void kernel_launch(void* const* d_in, const int* in_sizes, int n_in,
                              void* d_out, int out_size, void* d_ws, size_t ws_size,
                              hipStream_t stream)
{
    const float* x  = (const float*)d_in[0];
    const float* Wq = (const float*)d_in[1];
    const float* bq = (const float*)d_in[2];
    const float* Wk = (const float*)d_in[3];
    const float* bk = (const float*)d_in[4];
    const float* Wv = (const float*)d_in[5];
    const float* bv = (const float*)d_in[6];
    const float* Wo = (const float*)d_in[7];
    const float* bo = (const float*)d_in[8];
    const float* qp = (const float*)d_in[9];
    float* out = (float*)d_out;

    float* qb     = (float*)d_ws;
    float* kb     = qb + QKV_ELEMS;
    float* vb     = kb + QKV_ELEMS;
    float* merged = vb + QKV_ELEMS;
    float* part   = merged + QKV_ELEMS;   // 8.4 MB; total ws ~14.1 MB

    void* args[] = {(void*)&x, (void*)&Wq, (void*)&bq, (void*)&Wk, (void*)&bk,
                    (void*)&Wv, (void*)&bv, (void*)&Wo, (void*)&bo, (void*)&qp,
                    (void*)&qb, (void*)&kb, (void*)&vb, (void*)&part,
                    (void*)&merged, (void*)&out};
    hipError_t err = hipLaunchCooperativeKernel((const void*)mega_kernel,
                                                dim3(256), dim3(256),
                                                args, 0, stream);
    if (err != hipSuccess) {
        // Fallback: proven 5-kernel pipeline (round 7, passed @166us).
        fb_qkv_gemm<<<dim3(32, 24), 64, 0, stream>>>(x, Wq, bq, Wk, bk, Wv, bv, qb, kb, vb);
        qmap_inplace<<<384, 256, 0, stream>>>(qb, qp);
        fb_attn_partial<<<dim3(128, NCHUNK), 128, 0, stream>>>(qb, kb, vb, part);
        fb_attn_reduce<<<256, 256, 0, stream>>>(part, merged);
        fb_out_gemm<<<dim3(32, 8), 64, 0, stream>>>(merged, Wo, bo, out);
    }
}

// Round 12
// 184.166 us; speedup vs baseline: 1.5021x; 1.5021x over previous
//
#include <hip/hip_runtime.h>
#include <math.h>

// Sizes fixed by the problem: B=2, T=512, E=384, H=64, dk=6.
#define SEQ_T   512
#define E_DIM   384
#define H_NUM   64
#define DKQ     6
#define NROWS   1024
#define QKV_ELEMS (NROWS*E_DIM)
#define NCHUNK  4
#define INV_SQRT6 0.40824829046386296f

// ---------------------------------------------------------------------------
// Quantum layer, analytic form (validated on-device, rounds 5/7/10):
//   z_i = cos(a_i)cos(b_i)*cos(x_i) - sin(b_i)*sin(x_i)
//   o0 = z1 z2 z3 z4 z5 ; o1 = z0 z1 ; o_k = o_{k-1} * z_k  (k=2..5)
// ---------------------------------------------------------------------------
__device__ __forceinline__ void qmap6(const float* __restrict__ in,
                                      const float* __restrict__ AB,
                                      float* __restrict__ out)
{
    float z[6];
#pragma unroll
    for (int i = 0; i < 6; ++i) {
        float s, c;
        sincosf(in[i], &s, &c);
        z[i] = AB[i] * c - AB[6 + i] * s;
    }
    float z01 = z[0] * z[1];
    float z12 = z[1] * z[2];
    float z34 = z[3] * z[4];
    out[0] = z12 * z34 * z[5];
    out[1] = z01;
    out[2] = z01 * z[2];
    out[3] = out[2] * z[3];
    out[4] = out[3] * z[4];
    out[5] = out[4] * z[5];
}

// ---------------------------------------------------------------------------
// K1: Y = x @ [Wq;Wk;Wv]^T + bias, then qmap (and 1/sqrt6 on Q), scattered
// to (B,H,T,6). grid (32,24), 64 thr (1 wave), tile 32x48, micro 4x6.
// Structure proven r7 (fb_qkv); epilogue proven r10 (mega S1).
// ---------------------------------------------------------------------------
__global__ __launch_bounds__(64)
void qkv_gemm_qmap(const float* __restrict__ x,
                   const float* __restrict__ Wq, const float* __restrict__ bq,
                   const float* __restrict__ Wk, const float* __restrict__ bk,
                   const float* __restrict__ Wv, const float* __restrict__ bv,
                   const float* __restrict__ qparams,
                   float* __restrict__ qb, float* __restrict__ kb, float* __restrict__ vb)
{
    __shared__ __align__(16) float xs[64][36];
    __shared__ __align__(16) float ws[64][52];
    const int tid = threadIdx.x;
    const int tx = tid & 7;
    const int ty = tid >> 3;
    const int n0 = blockIdx.x * 32;
    const int by = blockIdx.y;
    const int sel = by >> 3;                 // 0=Q,1=K,2=V
    const int e0 = (by & 7) * 48;

    const float* W; const float* bias; float* ob;
    if (sel == 0)      { W = Wq; bias = bq; ob = qb; }
    else if (sel == 1) { W = Wk; bias = bk; ob = kb; }
    else               { W = Wv; bias = bv; ob = vb; }

    float acc[4][6];
#pragma unroll
    for (int i = 0; i < 4; ++i)
#pragma unroll
        for (int j = 0; j < 6; ++j) acc[i][j] = 0.f;

    for (int kc = 0; kc < E_DIM; kc += 64) {
#pragma unroll
        for (int w = 0; w < 8; ++w) {
            const int idx = tid + 64 * w;
            const int row = idx & 31;
            const int kf  = idx >> 5;
            const float4 g = *reinterpret_cast<const float4*>(
                x + (size_t)(n0 + row) * E_DIM + kc + kf * 4);
            xs[kf * 4 + 0][row] = g.x; xs[kf * 4 + 1][row] = g.y;
            xs[kf * 4 + 2][row] = g.z; xs[kf * 4 + 3][row] = g.w;
        }
#pragma unroll
        for (int w = 0; w < 12; ++w) {
            const int idx = tid + 64 * w;
            const int c  = idx % 48;
            const int kf = idx / 48;
            const float4 g = *reinterpret_cast<const float4*>(
                W + (size_t)(e0 + c) * E_DIM + kc + kf * 4);
            ws[kf * 4 + 0][c] = g.x; ws[kf * 4 + 1][c] = g.y;
            ws[kf * 4 + 2][c] = g.z; ws[kf * 4 + 3][c] = g.w;
        }
        __syncthreads();
#pragma unroll 8
        for (int kk = 0; kk < 64; ++kk) {
            const float4 a = *reinterpret_cast<const float4*>(&xs[kk][ty * 4]);
            const float2 b0 = *reinterpret_cast<const float2*>(&ws[kk][tx * 6 + 0]);
            const float2 b1 = *reinterpret_cast<const float2*>(&ws[kk][tx * 6 + 2]);
            const float2 b2 = *reinterpret_cast<const float2*>(&ws[kk][tx * 6 + 4]);
            const float av[4] = {a.x, a.y, a.z, a.w};
            const float bv6[6] = {b0.x, b0.y, b1.x, b1.y, b2.x, b2.y};
#pragma unroll
            for (int i = 0; i < 4; ++i)
#pragma unroll
                for (int j = 0; j < 6; ++j) acc[i][j] += av[i] * bv6[j];
        }
        __syncthreads();
    }

    // Epilogue: bias + qmap (+ 1/sqrt6 baked into Q), scatter (B,H,T,6)
    float AB[12];
#pragma unroll
    for (int i = 0; i < 6; ++i) {
        const float a = qparams[i * 2 + 0];
        const float b = qparams[i * 2 + 1];
        AB[i]     = cosf(a) * cosf(b);
        AB[6 + i] = sinf(b);
    }
    const int h = (e0 / 6) + tx;             // one full head slice per thread
    const float2 bi0 = *reinterpret_cast<const float2*>(bias + e0 + tx * 6 + 0);
    const float2 bi1 = *reinterpret_cast<const float2*>(bias + e0 + tx * 6 + 2);
    const float2 bi2 = *reinterpret_cast<const float2*>(bias + e0 + tx * 6 + 4);
    const float qs = (sel == 0) ? INV_SQRT6 : 1.0f;
#pragma unroll
    for (int i = 0; i < 4; ++i) {
        const int n = n0 + ty * 4 + i;       // b*512 + t
        const int b = n >> 9;
        const int t = n & 511;
        float y[6] = {acc[i][0] + bi0.x, acc[i][1] + bi0.y,
                      acc[i][2] + bi1.x, acc[i][3] + bi1.y,
                      acc[i][4] + bi2.x, acc[i][5] + bi2.y};
        float o[6];
        qmap6(y, AB, o);
        float* rp = ob + (((size_t)(b * H_NUM + h) * SEQ_T) + t) * DKQ;
        float2 w0 = {o[0] * qs, o[1] * qs};
        float2 w1 = {o[2] * qs, o[3] * qs};
        float2 w2 = {o[4] * qs, o[5] * qs};
        *reinterpret_cast<float2*>(rp + 0) = w0;
        *reinterpret_cast<float2*>(rp + 2) = w1;
        *reinterpret_cast<float2*>(rp + 4) = w2;
    }
}

// ---------------------------------------------------------------------------
// K2: attention partial sums (q already scaled). grid (128 bh, 4 chunks),
// 128 thr (2 waves); each thread 4 q-rows over a 128-row s-chunk in LDS.
// No max subtraction (|score| <= sqrt(6)). Proven r7/r10.
// part layout: [c][q][bh][8] = acc[0..5], den, pad.
// ---------------------------------------------------------------------------
__global__ __launch_bounds__(128)
void attn_partial(const float* __restrict__ qb,
                  const float* __restrict__ kb,
                  const float* __restrict__ vb,
                  float* __restrict__ part)
{
    __shared__ __align__(16) float kv[128][12];
    const int bh = blockIdx.x;
    const int c  = blockIdx.y;
    const int t  = threadIdx.x;
    {
        const float* kr = kb + ((size_t)bh * SEQ_T + c * 128 + t) * DKQ;
        const float* vr = vb + ((size_t)bh * SEQ_T + c * 128 + t) * DKQ;
        const float2 k0 = *reinterpret_cast<const float2*>(kr + 0);
        const float2 k1 = *reinterpret_cast<const float2*>(kr + 2);
        const float2 k2 = *reinterpret_cast<const float2*>(kr + 4);
        const float2 v0 = *reinterpret_cast<const float2*>(vr + 0);
        const float2 v1 = *reinterpret_cast<const float2*>(vr + 2);
        const float2 v2 = *reinterpret_cast<const float2*>(vr + 4);
        float4* kvp = reinterpret_cast<float4*>(&kv[t][0]);
        kvp[0] = make_float4(k0.x, k0.y, k1.x, k1.y);
        kvp[1] = make_float4(k2.x, k2.y, v0.x, v0.y);
        kvp[2] = make_float4(v1.x, v1.y, v2.x, v2.y);
    }
    float qrow[4][6];   // pre-scaled by 1/sqrt(6) in K1
#pragma unroll
    for (int r = 0; r < 4; ++r) {
        const float* qp = qb + ((size_t)bh * SEQ_T + r * 128 + t) * DKQ;
        const float2 q0 = *reinterpret_cast<const float2*>(qp + 0);
        const float2 q1 = *reinterpret_cast<const float2*>(qp + 2);
        const float2 q2 = *reinterpret_cast<const float2*>(qp + 4);
        qrow[r][0] = q0.x; qrow[r][1] = q0.y;
        qrow[r][2] = q1.x; qrow[r][3] = q1.y;
        qrow[r][4] = q2.x; qrow[r][5] = q2.y;
    }
    __syncthreads();
    float accv[4][6];
    float den[4] = {0.f, 0.f, 0.f, 0.f};
#pragma unroll
    for (int r = 0; r < 4; ++r)
#pragma unroll
        for (int d = 0; d < 6; ++d) accv[r][d] = 0.f;
    const float4* kv4 = reinterpret_cast<const float4*>(&kv[0][0]);
#pragma unroll 2
    for (int s = 0; s < 128; ++s) {
        const float4 r0 = kv4[3 * s + 0];
        const float4 r1 = kv4[3 * s + 1];
        const float4 r2 = kv4[3 * s + 2];
#pragma unroll
        for (int r = 0; r < 4; ++r) {
            const float sc = qrow[r][0] * r0.x + qrow[r][1] * r0.y + qrow[r][2] * r0.z
                           + qrow[r][3] * r0.w + qrow[r][4] * r1.x + qrow[r][5] * r1.y;
            const float e = __expf(sc);
            den[r] += e;
            accv[r][0] += e * r1.z; accv[r][1] += e * r1.w;
            accv[r][2] += e * r2.x; accv[r][3] += e * r2.y;
            accv[r][4] += e * r2.z; accv[r][5] += e * r2.w;
        }
    }
#pragma unroll
    for (int r = 0; r < 4; ++r) {
        const int q = r * 128 + t;
        float4* pp = reinterpret_cast<float4*>(
            part + ((size_t)((c * SEQ_T + q) * 128 + bh)) * 8);
        pp[0] = make_float4(accv[r][0], accv[r][1], accv[r][2], accv[r][3]);
        pp[1] = make_float4(accv[r][4], accv[r][5], den[r], 0.f);
    }
}

// ---------------------------------------------------------------------------
// K3: fused softmax-reduce + out gemm. grid (32,8), 64 thr, tile 32x48.
// Per block: (1) deninv[row][h] = 1/sum_c den into LDS; (2) build the 32x384
// merged rows from part directly into amg[row][k] ([32][385], stride 385 ==
// 1 mod 32 -> conflict-free scalar reads); (3) proven 6-chunk FMA loop.
// Eliminates the reduce kernel, the merged buffer, and one graph node.
// LDS total 69.3 KB (legal on gfx950's 160 KiB/CU).
// ---------------------------------------------------------------------------
__global__ __launch_bounds__(64)
void out_gemm_fused(const float* __restrict__ part,
                    const float* __restrict__ Wo, const float* __restrict__ bo,
                    float* __restrict__ out)
{
    __shared__ float deninv[32][65];                 // 8.3 KB
    __shared__ float amg[32][385];                   // merged rows, 49.3 KB
    __shared__ __align__(16) float ws[64][52];       // 13.3 KB

    const int tid = threadIdx.x;
    const int tx = tid & 7;
    const int ty = tid >> 3;
    const int n0 = blockIdx.x * 32;
    const int e0 = blockIdx.y * 48;
    const int b  = n0 >> 9;                          // 32-row blocks never straddle b
    const int q0 = n0 & 511;

    // (1) denominator sums: thread tid owns head h=tid for all 32 rows.
#pragma unroll 4
    for (int i = 0; i < 32; ++i) {
        float den = 0.f;
#pragma unroll
        for (int c = 0; c < NCHUNK; ++c)
            den += part[((size_t)((c * SEQ_T + q0 + i) * 128) + b * H_NUM + tid) * 8 + 6];
        deninv[i][tid] = 1.0f / den;
    }
    __syncthreads();

    // (2) merged rows: 32x384 elems, 192 per thread; amg[row][k].
#pragma unroll 4
    for (int i = 0; i < 192; ++i) {
        const int idx = tid + 64 * i;                // 0..12287
        const int k   = idx % E_DIM;
        const int row = idx / E_DIM;
        const int h = k / 6;
        const int d = k - h * 6;
        float s = 0.f;
#pragma unroll
        for (int c = 0; c < NCHUNK; ++c)
            s += part[((size_t)((c * SEQ_T + q0 + row) * 128) + b * H_NUM + h) * 8 + d];
        amg[row][k] = s * deninv[row][h];
    }
    __syncthreads();

    // (3) GEMM vs Wo^T, K=384 in 6 chunks (ws staging proven r7).
    float acc[4][6];
#pragma unroll
    for (int i = 0; i < 4; ++i)
#pragma unroll
        for (int j = 0; j < 6; ++j) acc[i][j] = 0.f;

    for (int kc = 0; kc < E_DIM; kc += 64) {
#pragma unroll
        for (int w = 0; w < 12; ++w) {
            const int idx = tid + 64 * w;
            const int c  = idx % 48;
            const int kf = idx / 48;
            const float4 g = *reinterpret_cast<const float4*>(
                Wo + (size_t)(e0 + c) * E_DIM + kc + kf * 4);
            ws[kf * 4 + 0][c] = g.x; ws[kf * 4 + 1][c] = g.y;
            ws[kf * 4 + 2][c] = g.z; ws[kf * 4 + 3][c] = g.w;
        }
        __syncthreads();
#pragma unroll 8
        for (int kk = 0; kk < 64; ++kk) {
            const int k = kc + kk;
            const float a0 = amg[ty * 4 + 0][k];
            const float a1 = amg[ty * 4 + 1][k];
            const float a2 = amg[ty * 4 + 2][k];
            const float a3 = amg[ty * 4 + 3][k];
            const float2 b0 = *reinterpret_cast<const float2*>(&ws[kk][tx * 6 + 0]);
            const float2 b1 = *reinterpret_cast<const float2*>(&ws[kk][tx * 6 + 2]);
            const float2 b2 = *reinterpret_cast<const float2*>(&ws[kk][tx * 6 + 4]);
            const float av[4] = {a0, a1, a2, a3};
            const float bv6[6] = {b0.x, b0.y, b1.x, b1.y, b2.x, b2.y};
#pragma unroll
            for (int i = 0; i < 4; ++i)
#pragma unroll
                for (int j = 0; j < 6; ++j) acc[i][j] += av[i] * bv6[j];
        }
        __syncthreads();
    }

    const float2 bi0 = *reinterpret_cast<const float2*>(bo + e0 + tx * 6 + 0);
    const float2 bi1 = *reinterpret_cast<const float2*>(bo + e0 + tx * 6 + 2);
    const float2 bi2 = *reinterpret_cast<const float2*>(bo + e0 + tx * 6 + 4);
#pragma unroll
    for (int i = 0; i < 4; ++i) {
        const int n = n0 + ty * 4 + i;
        float* rp = out + (size_t)n * E_DIM + e0 + tx * 6;
        float2 w0 = {acc[i][0] + bi0.x, acc[i][1] + bi0.y};
        float2 w1 = {acc[i][2] + bi1.x, acc[i][3] + bi1.y};
        float2 w2 = {acc[i][4] + bi2.x, acc[i][5] + bi2.y};
        *reinterpret_cast<float2*>(rp + 0) = w0;
        *reinterpret_cast<float2*>(rp + 2) = w1;
        *reinterpret_cast<float2*>(rp + 4) = w2;
    }
}

// ---------------------------------------------------------------------------
extern "C" void kernel_launch(void* const* d_in, const int* in_sizes, int n_in,
                              void* d_out, int out_size, void* d_ws, size_t ws_size,
                              hipStream_t stream)
{
    const float* x  = (const float*)d_in[0];
    const float* Wq = (const float*)d_in[1];
    const float* bq = (const float*)d_in[2];
    const float* Wk = (const float*)d_in[3];
    const float* bk = (const float*)d_in[4];
    const float* Wv = (const float*)d_in[5];
    const float* bv = (const float*)d_in[6];
    const float* Wo = (const float*)d_in[7];
    const float* bo = (const float*)d_in[8];
    const float* qp = (const float*)d_in[9];
    float* out = (float*)d_out;

    float* qb   = (float*)d_ws;
    float* kb   = qb + QKV_ELEMS;
    float* vb   = kb + QKV_ELEMS;
    float* part = vb + QKV_ELEMS;      // 4*512*128*8 floats = 8.4 MB; total ~12.9 MB

    qkv_gemm_qmap<<<dim3(32, 24), 64, 0, stream>>>(x, Wq, bq, Wk, bk, Wv, bv, qp, qb, kb, vb);
    attn_partial<<<dim3(128, NCHUNK), 128, 0, stream>>>(qb, kb, vb, part);
    out_gemm_fused<<<dim3(32, 8), 64, 0, stream>>>(part, Wo, bo, out);
}